// Round 8
// baseline (2207.286 us; speedup 1.0000x reference)
//
#include <hip/hip_runtime.h>

// R8: single-kernel producer/consumer.
//  blocks 0..15  = CONSUMER: R5/R7's proven scan (656 cy/step, byte-identical body).
//  blocks 16..79 = PRODUCERS: 4 per batch-group; producer (g,q) computes
//      xp[t][bbase..bbase+16)[0..128) for t == q (mod 4) into d_ws, LEAD-free,
//      publishing monotonic progress via ready[g][q] (release, agent scope).
//  Consumer polls min(ready[g][0..3]) with ACQUIRE loads once per 32-step span
//  (margin 36 >> prefetch depth 4). Acquire also invalidates stale L1/L2 lines
//  from the previous graph replay (producers may run on a different XCD).
//  R6 lesson respected: producers share NOTHING with the scan's barrier loop.
//  Fallbacks: serial two-kernel (R7) if ws lacks counter space; R2 fused if <256MB.

#define SEQ   4096
#define BATCH 256
#define DIN   64
#define DH    128
#define XSTEP (BATCH * DIN)
#define XP_BYTES ((size_t)SEQ * BATCH * DH * 2)

typedef _Float16 half8  __attribute__((ext_vector_type(8)));
typedef _Float16 half4v __attribute__((ext_vector_type(4)));
typedef _Float16 half2v __attribute__((ext_vector_type(2)));
typedef __fp16   fp16x2 __attribute__((ext_vector_type(2)));
typedef float    f32x4  __attribute__((ext_vector_type(4)));
typedef float    f32x2  __attribute__((ext_vector_type(2)));

union H2 { fp16x2 q; half2v h; unsigned int u; };

__device__ __forceinline__ float fast_tanh(float v) {
    float e = __builtin_amdgcn_exp2f(v * 2.88539008177792681472f);
    return 1.0f - 2.0f * __builtin_amdgcn_rcpf(e + 1.0f);
}

__device__ __forceinline__ half2v pk(float a, float b) {
    H2 u; u.q = __builtin_amdgcn_cvt_pkrtz(a, b);
    return u.h;
}

__device__ __forceinline__ half8 cvt8(f32x4 a, f32x4 b) {
    half2v p0 = pk(a[0], a[1]);
    half2v p1 = pk(a[2], a[3]);
    half2v p2 = pk(b[0], b[1]);
    half2v p3 = pk(b[2], b[3]);
    half8 r;
    r[0] = p0[0]; r[1] = p0[1]; r[2] = p1[0]; r[3] = p1[1];
    r[4] = p2[0]; r[5] = p2[1]; r[6] = p3[0]; r[7] = p3[1];
    return r;
}

__device__ __forceinline__ half4v pack4(f32x4 a) {
    half2v q0 = pk(a[0], a[1]);
    half2v q1 = pk(a[2], a[3]);
    half4v r;
    r[0] = q0[0]; r[1] = q0[1]; r[2] = q1[0]; r[3] = q1[1];
    return r;
}

__device__ __forceinline__ f32x4 cvt4f(half4v v) {
    f32x4 r;
    r[0] = (float)v[0]; r[1] = (float)v[1];
    r[2] = (float)v[2]; r[3] = (float)v[3];
    return r;
}

// byte offset of h[b][j] (f16) in a [16][128] tile; 16B-chunk XOR swizzle by b.
__device__ __forceinline__ int hoff(int b, int j) {
    return b * 256 + ((((j >> 3) ^ b) & 15) << 4) + (j & 7) * 2;
}

struct XSlot { f32x4 v0, v1, v2, v3; };
#define XLOAD(slot, p_) do {                                           \
        (slot).v0 = *(const f32x4*)(p_);                               \
        (slot).v1 = *(const f32x4*)((p_) + 4);                         \
        (slot).v2 = *(const f32x4*)((p_) + 32);                        \
        (slot).v3 = *(const f32x4*)((p_) + 36);                        \
    } while (0)

// spin until 4*min(ready[0..3]) >= tgt; acquire loads give data visibility
// (incl. cross-XCD L2 invalidation) for everything released at that progress.
__device__ __forceinline__ void pollwait(const int* rdy, int tgt) {
    for (;;) {
        int r0 = __hip_atomic_load(rdy + 0, __ATOMIC_ACQUIRE, __HIP_MEMORY_SCOPE_AGENT);
        int r1 = __hip_atomic_load(rdy + 1, __ATOMIC_ACQUIRE, __HIP_MEMORY_SCOPE_AGENT);
        int r2 = __hip_atomic_load(rdy + 2, __ATOMIC_ACQUIRE, __HIP_MEMORY_SCOPE_AGENT);
        int r3 = __hip_atomic_load(rdy + 3, __ATOMIC_ACQUIRE, __HIP_MEMORY_SCOPE_AGENT);
        int m = r0 < r1 ? r0 : r1;
        int n = r2 < r3 ? r2 : r3;
        if (n < m) m = n;
        if (4 * m >= tgt) return;
        __builtin_amdgcn_s_sleep(8);
    }
}

__launch_bounds__(512, 1)
__global__ void rnn_pc(const float* __restrict__ x,     // [SEQ][BATCH][DIN]
                       const float* __restrict__ Wih,   // [DH][DIN]
                       const float* __restrict__ bih,   // [DH]
                       const float* __restrict__ Whh,   // [DH][DH]
                       const float* __restrict__ bhh,   // [DH]
                       float* __restrict__ out,         // [BATCH][DH]
                       _Float16* __restrict__ xp,       // [SEQ][BATCH][DH] in d_ws
                       int* __restrict__ ready)         // [16][4], zeroed per launch
{
    __shared__ __align__(16) char hbuf[8192];   // consumer: 2 x swizzled [16][128] f16

    const int tid  = threadIdx.x;
    const int wave = tid >> 6;
    const int lane = tid & 63;
    const int lb   = lane & 15;
    const int lg   = lane >> 4;

    if (blockIdx.x < 16) {
        // ========================= CONSUMER (scan) =========================
        const int g     = blockIdx.x;
        const int bbase = g << 4;
        const int jbase = wave << 4;
        const int* rdy  = ready + g * 4;

        half8 Ahh[4];
        #pragma unroll
        for (int kt = 0; kt < 4; ++kt) {
            const float* wr = Whh + (jbase + lb) * DH + kt * 32 + (lg << 3);
            half8 f;
            #pragma unroll
            for (int i = 0; i < 8; ++i) f[i] = (_Float16)wr[i];
            Ahh[kt] = f;
        }

        // wait until xp[0..3] exist, then load the ring
        pollwait(rdy, 8);

        const _Float16* xpp = xp + (size_t)(bbase + lb) * DH + jbase + (lg << 2);
        const size_t XPS = (size_t)BATCH * DH;

        half4v xq1, xq2, xq3;
        f32x4 ci;
        {
            half4v x0 = *(const half4v*)(xpp);
            xq1 = *(const half4v*)(xpp + 1 * XPS);
            xq2 = *(const half4v*)(xpp + 2 * XPS);
            xq3 = *(const half4v*)(xpp + 3 * XPS);
            ci = cvt4f(x0);
        }
        const _Float16* xload = xpp + 4 * XPS;

        half8 hf0, hf1, hf2, hf3;
        {
            half8 z;
            #pragma unroll
            for (int i = 0; i < 8; ++i) z[i] = (_Float16)0.0f;
            hf0 = hf1 = hf2 = hf3 = z;   // h_0 = 0
        }

        const int woff  = hoff(lb, jbase + (lg << 2));
        const int roff0 = hoff(lb, 0 * 32 + (lg << 3));
        const int roff1 = hoff(lb, 1 * 32 + (lg << 3));
        const int roff2 = hoff(lb, 2 * 32 + (lg << 3));
        const int roff3 = hoff(lb, 3 * 32 + (lg << 3));

        #define SCAN_BODY(T_) do {                                                   \
            const int t_ = (T_);                                                     \
            char* hb = hbuf + (((t_ + 1) & 1) << 12);                                \
            f32x4 zz = {0.0f, 0.0f, 0.0f, 0.0f};                                     \
            f32x4 acc1, acc2;                                                        \
            acc1 = __builtin_amdgcn_mfma_f32_16x16x32_f16(Ahh[0], hf0, ci,   0,0,0); \
            acc2 = __builtin_amdgcn_mfma_f32_16x16x32_f16(Ahh[2], hf2, zz,   0,0,0); \
            acc1 = __builtin_amdgcn_mfma_f32_16x16x32_f16(Ahh[1], hf1, acc1, 0,0,0); \
            acc2 = __builtin_amdgcn_mfma_f32_16x16x32_f16(Ahh[3], hf3, acc2, 0,0,0); \
            half4v xnew = *(const half4v*)xload;                                     \
            if (t_ + 5 < SEQ) xload += XPS;                                          \
            f32x4 rA;                                                                \
            _Pragma("unroll")                                                        \
            for (int r = 0; r < 4; ++r) rA[r] = fast_tanh(acc1[r] + acc2[r]);        \
            *(half4v*)(hb + woff) = pack4(rA);                                       \
            ci = cvt4f(xq1);                                                         \
            xq1 = xq2; xq2 = xq3; xq3 = xnew;                                        \
            asm volatile("s_waitcnt lgkmcnt(0)" ::: "memory");                       \
            __builtin_amdgcn_s_barrier();                                            \
            asm volatile("" ::: "memory");                                           \
            hf0 = *(const half8*)(hb + roff0);                                       \
            hf2 = *(const half8*)(hb + roff2);                                       \
            hf1 = *(const half8*)(hb + roff1);                                       \
            hf3 = *(const half8*)(hb + roff3);                                       \
        } while (0)

        // main spans: 127 x 32 steps (t = 0..4063)
        for (int T = 0; T < 4064; T += 32) {
            pollwait(rdy, T + 36);   // covers prefetch up to T+35
            #pragma unroll 2
            for (int tt = 0; tt < 32; ++tt) SCAN_BODY(T + tt);
        }
        // tail span: t = 4064..4094 (needs xp up to 4095 -> full coverage)
        pollwait(rdy, 4096);
        #pragma unroll 2
        for (int t = 4064; t < 4095; ++t) SCAN_BODY(t);

        // epilogue: t = SEQ-1 -> h_final -> out (f32)
        {
            f32x4 zz = {0.0f, 0.0f, 0.0f, 0.0f};
            f32x4 acc1, acc2;
            acc1 = __builtin_amdgcn_mfma_f32_16x16x32_f16(Ahh[0], hf0, ci,   0, 0, 0);
            acc2 = __builtin_amdgcn_mfma_f32_16x16x32_f16(Ahh[2], hf2, zz,   0, 0, 0);
            acc1 = __builtin_amdgcn_mfma_f32_16x16x32_f16(Ahh[1], hf1, acc1, 0, 0, 0);
            acc2 = __builtin_amdgcn_mfma_f32_16x16x32_f16(Ahh[3], hf3, acc2, 0, 0, 0);
            f32x4 rA;
            #pragma unroll
            for (int r = 0; r < 4; ++r) rA[r] = fast_tanh(acc1[r] + acc2[r]);
            *(f32x4*)(out + (size_t)(bbase + lb) * DH + jbase + (lg << 2)) = rA;
        }
        #undef SCAN_BODY
    } else {
        // ========================= PRODUCER =========================
        // block p = (g,q): xp[t][bbase..bbase+16) for t == q (mod 4).
        // wave w at iteration i handles k = 8i+w, t = q + 4k. After iter i the
        // class has k < 8(i+1) complete -> ready[g][q] = 8(i+1) (release).
        const int p  = blockIdx.x - 16;   // 0..63
        const int g  = p >> 2;
        const int q  = p & 3;
        const int bb = g << 4;

        half8 A[8][2];
        #pragma unroll
        for (int s = 0; s < 8; ++s) {
            #pragma unroll
            for (int kt = 0; kt < 2; ++kt) {
                const float* wr = Wih + (s * 16 + lb) * DIN + kt * 32 + (lg << 3);
                half8 f;
                #pragma unroll
                for (int i = 0; i < 8; ++i) f[i] = (_Float16)wr[i];
                A[s][kt] = f;
            }
        }
        f32x4 bias[8];
        #pragma unroll
        for (int s = 0; s < 8; ++s)
            #pragma unroll
            for (int r = 0; r < 4; ++r) {
                int j = s * 16 + (lg << 2) + r;
                bias[s][r] = bih[j] + bhh[j];
            }

        // prefetch x for iteration 0
        XSlot xs;
        {
            int t0 = q + (wave << 2);
            XLOAD(xs, x + ((size_t)t0 * BATCH + bb + lb) * DIN + (lg << 3));
        }

        for (int i = 0; i < 128; ++i) {
            const int t = q + ((((i << 3) + wave)) << 2);

            half8 xf0 = cvt8(xs.v0, xs.v1);
            half8 xf1 = cvt8(xs.v2, xs.v3);

            // prefetch next iteration's x (hides HBM latency under MFMA)
            XSlot xn;
            if (i + 1 < 128) {
                int tn = q + (((((i + 1) << 3) + wave)) << 2);
                XLOAD(xn, x + ((size_t)tn * BATCH + bb + lb) * DIN + (lg << 3));
            }

            _Float16* op = xp + ((size_t)t * BATCH + bb + lb) * DH + (lg << 2);
            #pragma unroll
            for (int s = 0; s < 8; ++s) {
                f32x4 acc;
                acc = __builtin_amdgcn_mfma_f32_16x16x32_f16(A[s][0], xf0, bias[s], 0, 0, 0);
                acc = __builtin_amdgcn_mfma_f32_16x16x32_f16(A[s][1], xf1, acc,     0, 0, 0);
                *(half4v*)(op + s * 16) = pack4(acc);
            }
            if (i + 1 < 128) xs = xn;

            // drains each wave's stores (vmcnt) before the barrier
            __syncthreads();

            // publish progress: frequently at startup, then every 4 iters
            if (tid == 0 && (i < 8 || (i & 3) == 3)) {
                __hip_atomic_store(&ready[g * 4 + q], 8 * (i + 1),
                                   __ATOMIC_RELEASE, __HIP_MEMORY_SCOPE_AGENT);
            }
        }
    }
}

// ---------------------------------------------------------------------------
// Fallback 1 (R7 serial two-kernel, proven 1416 us) if no room for counters.
// ---------------------------------------------------------------------------
__launch_bounds__(256)
__global__ void rnn_prepass(const float* __restrict__ x,
                            const float* __restrict__ Wih,
                            const float* __restrict__ bih,
                            const float* __restrict__ bhh,
                            _Float16* __restrict__ xp)
{
    const int tid  = threadIdx.x;
    const int w    = tid >> 6;
    const int lane = tid & 63;
    const int lb   = lane & 15;
    const int lg   = lane >> 4;
    const int rowbase = blockIdx.x * 64 + w * 16;

    half8 A[8][2];
    #pragma unroll
    for (int s = 0; s < 8; ++s)
        #pragma unroll
        for (int kt = 0; kt < 2; ++kt) {
            const float* wr = Wih + (s * 16 + lb) * DIN + kt * 32 + lg * 8;
            half8 f;
            #pragma unroll
            for (int i = 0; i < 8; ++i) f[i] = (_Float16)wr[i];
            A[s][kt] = f;
        }
    f32x4 bias[8];
    #pragma unroll
    for (int s = 0; s < 8; ++s)
        #pragma unroll
        for (int r = 0; r < 4; ++r) {
            int j = s * 16 + lg * 4 + r;
            bias[s][r] = bih[j] + bhh[j];
        }

    const float* xr = x + (size_t)(rowbase + lb) * DIN + lg * 8;
    half8 xf0 = cvt8(*(const f32x4*)(xr),      *(const f32x4*)(xr + 4));
    half8 xf1 = cvt8(*(const f32x4*)(xr + 32), *(const f32x4*)(xr + 36));

    _Float16* op = xp + (size_t)(rowbase + lb) * DH + lg * 4;
    #pragma unroll
    for (int s = 0; s < 8; ++s) {
        f32x4 acc;
        acc = __builtin_amdgcn_mfma_f32_16x16x32_f16(A[s][0], xf0, bias[s], 0, 0, 0);
        acc = __builtin_amdgcn_mfma_f32_16x16x32_f16(A[s][1], xf1, acc,     0, 0, 0);
        *(half4v*)(op + s * 16) = pack4(acc);
    }
}

__launch_bounds__(512, 1)
__global__ void rnn_scan_xp(const _Float16* __restrict__ xp,
                            const float* __restrict__ Whh,
                            float* __restrict__ out)
{
    __shared__ __align__(16) char hbuf[8192];

    const int tid   = threadIdx.x;
    const int wave  = tid >> 6;
    const int lane  = tid & 63;
    const int lb    = lane & 15;
    const int lg    = lane >> 4;
    const int bbase = blockIdx.x << 4;
    const int jbase = wave << 4;

    half8 Ahh[4];
    #pragma unroll
    for (int kt = 0; kt < 4; ++kt) {
        const float* wr = Whh + (jbase + lb) * DH + kt * 32 + lg * 8;
        half8 f;
        #pragma unroll
        for (int i = 0; i < 8; ++i) f[i] = (_Float16)wr[i];
        Ahh[kt] = f;
    }

    const _Float16* xpp = xp + (size_t)(bbase + lb) * DH + jbase + (lg << 2);
    const size_t XPS = (size_t)BATCH * DH;

    half4v xq1, xq2, xq3;
    f32x4 ci;
    {
        half4v x0 = *(const half4v*)(xpp);
        xq1 = *(const half4v*)(xpp + 1 * XPS);
        xq2 = *(const half4v*)(xpp + 2 * XPS);
        xq3 = *(const half4v*)(xpp + 3 * XPS);
        ci = cvt4f(x0);
    }
    const _Float16* xload = xpp + 4 * XPS;

    half8 hf0, hf1, hf2, hf3;
    {
        half8 z;
        #pragma unroll
        for (int i = 0; i < 8; ++i) z[i] = (_Float16)0.0f;
        hf0 = hf1 = hf2 = hf3 = z;
    }

    const int woff  = hoff(lb, jbase + (lg << 2));
    const int roff0 = hoff(lb, 0 * 32 + (lg << 3));
    const int roff1 = hoff(lb, 1 * 32 + (lg << 3));
    const int roff2 = hoff(lb, 2 * 32 + (lg << 3));
    const int roff3 = hoff(lb, 3 * 32 + (lg << 3));

    #pragma unroll 2
    for (int t = 0; t < SEQ - 1; ++t) {
        const int nb = (t + 1) & 1;
        char* hb = hbuf + nb * 4096;

        f32x4 zz = {0.0f, 0.0f, 0.0f, 0.0f};
        f32x4 acc1, acc2;
        acc1 = __builtin_amdgcn_mfma_f32_16x16x32_f16(Ahh[0], hf0, ci,   0, 0, 0);
        acc2 = __builtin_amdgcn_mfma_f32_16x16x32_f16(Ahh[2], hf2, zz,   0, 0, 0);
        acc1 = __builtin_amdgcn_mfma_f32_16x16x32_f16(Ahh[1], hf1, acc1, 0, 0, 0);
        acc2 = __builtin_amdgcn_mfma_f32_16x16x32_f16(Ahh[3], hf3, acc2, 0, 0, 0);

        half4v xnew = *(const half4v*)xload;
        if (t + 5 < SEQ) xload += XPS;

        f32x4 rA;
        #pragma unroll
        for (int r = 0; r < 4; ++r) rA[r] = fast_tanh(acc1[r] + acc2[r]);
        *(half4v*)(hb + woff) = pack4(rA);

        ci = cvt4f(xq1);
        xq1 = xq2; xq2 = xq3; xq3 = xnew;

        asm volatile("s_waitcnt lgkmcnt(0)" ::: "memory");
        __builtin_amdgcn_s_barrier();
        asm volatile("" ::: "memory");

        hf0 = *(const half8*)(hb + roff0);
        hf2 = *(const half8*)(hb + roff2);
        hf1 = *(const half8*)(hb + roff1);
        hf3 = *(const half8*)(hb + roff3);
    }

    {
        f32x4 zz = {0.0f, 0.0f, 0.0f, 0.0f};
        f32x4 acc1, acc2;
        acc1 = __builtin_amdgcn_mfma_f32_16x16x32_f16(Ahh[0], hf0, ci,   0, 0, 0);
        acc2 = __builtin_amdgcn_mfma_f32_16x16x32_f16(Ahh[2], hf2, zz,   0, 0, 0);
        acc1 = __builtin_amdgcn_mfma_f32_16x16x32_f16(Ahh[1], hf1, acc1, 0, 0, 0);
        acc2 = __builtin_amdgcn_mfma_f32_16x16x32_f16(Ahh[3], hf3, acc2, 0, 0, 0);
        f32x4 rA;
        #pragma unroll
        for (int r = 0; r < 4; ++r) rA[r] = fast_tanh(acc1[r] + acc2[r]);
        *(f32x4*)(out + (size_t)(bbase + lb) * DH + jbase + (lg << 2)) = rA;
    }
}

// ---------------------------------------------------------------------------
// Fallback 2 (R2 fused, proven 1768 us) if d_ws < 256 MB.
// ---------------------------------------------------------------------------
__device__ __forceinline__ int hoffc(int b, int chunk, int lo) {
    return b * 256 + ((chunk ^ b) << 4) + lo;
}
__device__ __forceinline__ int xoff_lds(int b, int chunk, int lo) {
    return b * 128 + (((chunk ^ (b & 7)) << 4) + lo);
}

__launch_bounds__(512, 1)
__global__ void rnn_fused_scan_r2(const float* __restrict__ x,
                                  const float* __restrict__ Wih,
                                  const float* __restrict__ bih,
                                  const float* __restrict__ Whh,
                                  const float* __restrict__ bhh,
                                  float* __restrict__ out)
{
    __shared__ __align__(16) char lds[12288];
    char* hbuf = lds;
    char* xbuf = lds + 8192;

    const int tid   = threadIdx.x;
    const int wave  = tid >> 6;
    const int lane  = tid & 63;
    const int lb    = lane & 15;
    const int lg    = lane >> 4;
    const int bbase = blockIdx.x << 4;
    const int jbase = wave << 4;

    half8 Ahh[4], Aih[2];
    #pragma unroll
    for (int kt = 0; kt < 4; ++kt) {
        const float* wr = Whh + (jbase + lb) * DH + kt * 32 + lg * 8;
        half8 f;
        #pragma unroll
        for (int i = 0; i < 8; ++i) f[i] = (_Float16)wr[i];
        Ahh[kt] = f;
    }
    #pragma unroll
    for (int kt = 0; kt < 2; ++kt) {
        const float* wr = Wih + (jbase + lb) * DIN + kt * 32 + lg * 8;
        half8 f;
        #pragma unroll
        for (int i = 0; i < 8; ++i) f[i] = (_Float16)wr[i];
        Aih[kt] = f;
    }
    f32x4 bias;
    #pragma unroll
    for (int r = 0; r < 4; ++r) {
        int j = jbase + lg * 4 + r;
        bias[r] = bih[j] + bhh[j];
    }

    const int bx = tid >> 5;
    const int kx = (tid & 31) << 1;
    const float* xlane = x + (size_t)(bbase + bx) * DIN + kx;

    f32x2 r0  = *(const f32x2*)(xlane + 0 * (size_t)XSTEP);
    f32x2 rx0 = *(const f32x2*)(xlane + 1 * (size_t)XSTEP);
    f32x2 rx1 = *(const f32x2*)(xlane + 2 * (size_t)XSTEP);
    f32x2 rx2 = *(const f32x2*)(xlane + 3 * (size_t)XSTEP);
    {
        half2v p; p[0] = (_Float16)r0[0]; p[1] = (_Float16)r0[1];
        *(half2v*)(xbuf + xoff_lds(bx, kx >> 3, (kx & 7) * 2)) = p;
    }
    const float* xload = xlane + 4 * (size_t)XSTEP;

    half8 hf0, hf1, hf2, hf3, xf0, xf1;
    {
        half8 z;
        #pragma unroll
        for (int i = 0; i < 8; ++i) z[i] = (_Float16)0.0f;
        hf0 = hf1 = hf2 = hf3 = z;
    }

    asm volatile("s_waitcnt lgkmcnt(0)" ::: "memory");
    __builtin_amdgcn_s_barrier();
    asm volatile("" ::: "memory");
    xf0 = *(const half8*)(xbuf + xoff_lds(lb, 0 * 4 + lg, 0));
    xf1 = *(const half8*)(xbuf + xoff_lds(lb, 1 * 4 + lg, 0));

    f32x4 acc_ih;
    acc_ih = __builtin_amdgcn_mfma_f32_16x16x32_f16(Aih[0], xf0, bias,   0, 0, 0);
    acc_ih = __builtin_amdgcn_mfma_f32_16x16x32_f16(Aih[1], xf1, acc_ih, 0, 0, 0);

    #pragma unroll 2
    for (int t = 0; t < SEQ - 1; ++t) {
        f32x4 zz = {0.0f, 0.0f, 0.0f, 0.0f};
        f32x4 acc1, acc2;
        acc1 = __builtin_amdgcn_mfma_f32_16x16x32_f16(Ahh[0], hf0, acc_ih, 0, 0, 0);
        acc2 = __builtin_amdgcn_mfma_f32_16x16x32_f16(Ahh[2], hf2, zz,     0, 0, 0);
        acc1 = __builtin_amdgcn_mfma_f32_16x16x32_f16(Ahh[1], hf1, acc1,   0, 0, 0);
        acc2 = __builtin_amdgcn_mfma_f32_16x16x32_f16(Ahh[3], hf3, acc2,   0, 0, 0);

        const int nb = (t + 1) & 1;
        {
            half2v p; p[0] = (_Float16)rx0[0]; p[1] = (_Float16)rx0[1];
            *(half2v*)(xbuf + nb * 2048 + xoff_lds(bx, kx >> 3, (kx & 7) * 2)) = p;
        }
        rx0 = rx1; rx1 = rx2;
        rx2 = *(const f32x2*)xload;
        if (t + 5 < SEQ) xload += XSTEP;

        f32x4 hv;
        #pragma unroll
        for (int r = 0; r < 4; ++r) hv[r] = fast_tanh(acc1[r] + acc2[r]);
        {
            half4v p;
            #pragma unroll
            for (int r = 0; r < 4; ++r) p[r] = (_Float16)hv[r];
            *(half4v*)(hbuf + nb * 4096 + hoffc(lb, (wave << 1) + (lg >> 1), (lg & 1) * 8)) = p;
        }

        asm volatile("s_waitcnt lgkmcnt(0)" ::: "memory");
        __builtin_amdgcn_s_barrier();
        asm volatile("" ::: "memory");

        hf0 = *(const half8*)(hbuf + nb * 4096 + hoffc(lb, 0 * 4 + lg, 0));
        hf2 = *(const half8*)(hbuf + nb * 4096 + hoffc(lb, 2 * 4 + lg, 0));
        hf1 = *(const half8*)(hbuf + nb * 4096 + hoffc(lb, 1 * 4 + lg, 0));
        hf3 = *(const half8*)(hbuf + nb * 4096 + hoffc(lb, 3 * 4 + lg, 0));
        xf0 = *(const half8*)(xbuf + nb * 2048 + xoff_lds(lb, 0 * 4 + lg, 0));
        xf1 = *(const half8*)(xbuf + nb * 2048 + xoff_lds(lb, 1 * 4 + lg, 0));

        acc_ih = __builtin_amdgcn_mfma_f32_16x16x32_f16(Aih[0], xf0, bias,   0, 0, 0);
        acc_ih = __builtin_amdgcn_mfma_f32_16x16x32_f16(Aih[1], xf1, acc_ih, 0, 0, 0);
    }

    {
        f32x4 zz = {0.0f, 0.0f, 0.0f, 0.0f};
        f32x4 acc1, acc2;
        acc1 = __builtin_amdgcn_mfma_f32_16x16x32_f16(Ahh[0], hf0, acc_ih, 0, 0, 0);
        acc2 = __builtin_amdgcn_mfma_f32_16x16x32_f16(Ahh[2], hf2, zz,     0, 0, 0);
        acc1 = __builtin_amdgcn_mfma_f32_16x16x32_f16(Ahh[1], hf1, acc1,   0, 0, 0);
        acc2 = __builtin_amdgcn_mfma_f32_16x16x32_f16(Ahh[3], hf3, acc2,   0, 0, 0);
        f32x4 res;
        #pragma unroll
        for (int r = 0; r < 4; ++r) res[r] = fast_tanh(acc1[r] + acc2[r]);
        *(f32x4*)(out + (size_t)(bbase + lb) * DH + jbase + (lg << 2)) = res;
    }
}

extern "C" void kernel_launch(void* const* d_in, const int* in_sizes, int n_in,
                              void* d_out, int out_size, void* d_ws, size_t ws_size,
                              hipStream_t stream) {
    const float* x   = (const float*)d_in[0];
    const float* Wih = (const float*)d_in[1];
    const float* bih = (const float*)d_in[2];
    const float* Whh = (const float*)d_in[3];
    const float* bhh = (const float*)d_in[4];
    float* out = (float*)d_out;

    if (ws_size >= XP_BYTES + 4096) {
        _Float16* xp = (_Float16*)d_ws;
        int* ready = (int*)((char*)d_ws + XP_BYTES);
        hipMemsetAsync(ready, 0, 4096, stream);   // zero counters each launch
        rnn_pc<<<80, 512, 0, stream>>>(x, Wih, bih, Whh, bhh, out, xp, ready);
    } else if (ws_size >= XP_BYTES) {
        _Float16* xp = (_Float16*)d_ws;
        rnn_prepass<<<SEQ * BATCH / 64, 256, 0, stream>>>(x, Wih, bih, bhh, xp);
        rnn_scan_xp<<<16, 512, 0, stream>>>(xp, Whh, out);
    } else {
        rnn_fused_scan_r2<<<16, 512, 0, stream>>>(x, Wih, bih, Whh, bhh, out);
    }
}

// Round 9
// 1314.143 us; speedup vs baseline: 1.6796x; 1.6796x over previous
//
#include <hip/hip_runtime.h>

// R9: two-kernel scheme (R7 structure, champion 1416 us). Overlap attempts
// (R6 intra-block helpers, R8 cross-block acquire/release) both SLOWED the
// scan by ~2x the prepass cost -- abandoned.
//  (1) rnn_prepass v3: FAT BLOCKS. 4096 blocks x 256 rows (was 16384 x 64):
//      the per-block W_ih fragment preamble (~20 VMEM/lane + 128 cvt) was
//      ~1:1 with the 16-MFMA body; 4 row-tiles per wave amortizes it 4x,
//      with software-pipelined x prefetch across tiles.
//  (2) rnn_scan_xp: BYTE-IDENTICAL to R5/R7 (1119 us, 656 cy/step, proven).
//  Fallback to the proven R2 fused kernel if ws_size < 256 MB.

#define SEQ   4096
#define BATCH 256
#define DIN   64
#define DH    128
#define XSTEP (BATCH * DIN)
#define XP_BYTES ((size_t)SEQ * BATCH * DH * 2)

typedef _Float16 half8  __attribute__((ext_vector_type(8)));
typedef _Float16 half4v __attribute__((ext_vector_type(4)));
typedef _Float16 half2v __attribute__((ext_vector_type(2)));
typedef __fp16   fp16x2 __attribute__((ext_vector_type(2)));
typedef float    f32x4  __attribute__((ext_vector_type(4)));
typedef float    f32x2  __attribute__((ext_vector_type(2)));

union H2 { fp16x2 q; half2v h; unsigned int u; };

// tanh(x) = 1 - 2/(1 + e^{2x}); overflow-free for all finite x.
__device__ __forceinline__ float fast_tanh(float v) {
    float e = __builtin_amdgcn_exp2f(v * 2.88539008177792681472f);
    return 1.0f - 2.0f * __builtin_amdgcn_rcpf(e + 1.0f);
}

__device__ __forceinline__ half2v pk(float a, float b) {
    H2 u; u.q = __builtin_amdgcn_cvt_pkrtz(a, b);
    return u.h;
}

__device__ __forceinline__ half8 cvt8(f32x4 a, f32x4 b) {
    half2v p0 = pk(a[0], a[1]);
    half2v p1 = pk(a[2], a[3]);
    half2v p2 = pk(b[0], b[1]);
    half2v p3 = pk(b[2], b[3]);
    half8 r;
    r[0] = p0[0]; r[1] = p0[1]; r[2] = p1[0]; r[3] = p1[1];
    r[4] = p2[0]; r[5] = p2[1]; r[6] = p3[0]; r[7] = p3[1];
    return r;
}

__device__ __forceinline__ half4v pack4(f32x4 a) {
    half2v q0 = pk(a[0], a[1]);
    half2v q1 = pk(a[2], a[3]);
    half4v r;
    r[0] = q0[0]; r[1] = q0[1]; r[2] = q1[0]; r[3] = q1[1];
    return r;
}

__device__ __forceinline__ f32x4 cvt4f(half4v v) {
    f32x4 r;
    r[0] = (float)v[0]; r[1] = (float)v[1];
    r[2] = (float)v[2]; r[3] = (float)v[3];
    return r;
}

// byte offset of h[b][j] (f16) in a [16][128] tile; 16B-chunk XOR swizzle by b.
__device__ __forceinline__ int hoff(int b, int j) {
    return b * 256 + ((((j >> 3) ^ b) & 15) << 4) + (j & 7) * 2;
}

struct XSlot { f32x4 v0, v1, v2, v3; };
#define XLOAD(slot, p_) do {                                           \
        (slot).v0 = *(const f32x4*)(p_);                               \
        (slot).v1 = *(const f32x4*)((p_) + 4);                         \
        (slot).v2 = *(const f32x4*)((p_) + 32);                        \
        (slot).v3 = *(const f32x4*)((p_) + 36);                        \
    } while (0)

// ---------------------------------------------------------------------------
// Kernel 1: prepass GEMM, v3 fat blocks.
// Block = 4 waves x 256 rows; wave w handles rows [blk*256 + w*64, +64) as
// 4 row-tiles of 16, weights loaded once, x prefetched one tile ahead.
// ---------------------------------------------------------------------------
__launch_bounds__(256)
__global__ void rnn_prepass(const float* __restrict__ x,     // [SEQ*BATCH][DIN]
                            const float* __restrict__ Wih,   // [DH][DIN]
                            const float* __restrict__ bih,   // [DH]
                            const float* __restrict__ bhh,   // [DH]
                            _Float16* __restrict__ xp)       // [SEQ*BATCH][DH]
{
    const int tid  = threadIdx.x;
    const int w    = tid >> 6;
    const int lane = tid & 63;
    const int lb   = lane & 15;
    const int lg   = lane >> 4;
    const int wbase = blockIdx.x * 256 + w * 64;   // this wave's 64-row span

    // A-frags: Wih for 8 j-subtiles x 2 k-halves (loaded ONCE per 64 rows)
    half8 A[8][2];
    #pragma unroll
    for (int s = 0; s < 8; ++s) {
        #pragma unroll
        for (int kt = 0; kt < 2; ++kt) {
            const float* wr = Wih + (s * 16 + lb) * DIN + kt * 32 + lg * 8;
            half8 f;
            #pragma unroll
            for (int i = 0; i < 8; ++i) f[i] = (_Float16)wr[i];
            A[s][kt] = f;
        }
    }
    f32x4 bias[8];
    #pragma unroll
    for (int s = 0; s < 8; ++s)
        #pragma unroll
        for (int r = 0; r < 4; ++r) {
            int j = s * 16 + lg * 4 + r;
            bias[s][r] = bih[j] + bhh[j];
        }

    // software-pipelined row-tiles: load tile r+1 while computing tile r
    XSlot xs, xn;
    XLOAD(xs, x + (size_t)(wbase + lb) * DIN + lg * 8);

    #pragma unroll
    for (int r = 0; r < 4; ++r) {
        const int row0 = wbase + r * 16;
        if (r < 3) {
            XLOAD(xn, x + (size_t)(row0 + 16 + lb) * DIN + lg * 8);
        }
        half8 xf0 = cvt8(xs.v0, xs.v1);
        half8 xf1 = cvt8(xs.v2, xs.v3);

        _Float16* op = xp + (size_t)(row0 + lb) * DH + lg * 4;
        #pragma unroll
        for (int s = 0; s < 8; ++s) {
            f32x4 acc;
            acc = __builtin_amdgcn_mfma_f32_16x16x32_f16(A[s][0], xf0, bias[s], 0, 0, 0);
            acc = __builtin_amdgcn_mfma_f32_16x16x32_f16(A[s][1], xf1, acc,     0, 0, 0);
            *(half4v*)(op + s * 16) = pack4(acc);
        }
        xs = xn;
    }
}

// ---------------------------------------------------------------------------
// Kernel 2: the scan. BYTE-IDENTICAL to R5/R7 (proven 1119 us, 656 cy/step).
// ---------------------------------------------------------------------------
__launch_bounds__(512, 1)
__global__ void rnn_scan_xp(const _Float16* __restrict__ xp,  // [SEQ][BATCH][DH]
                            const float* __restrict__ Whh,    // [DH][DH]
                            float* __restrict__ out)          // [BATCH][DH]
{
    __shared__ __align__(16) char hbuf[8192];   // 2 x swizzled [16][128] f16

    const int tid   = threadIdx.x;
    const int wave  = tid >> 6;
    const int lane  = tid & 63;
    const int lb    = lane & 15;
    const int lg    = lane >> 4;
    const int bbase = blockIdx.x << 4;
    const int jbase = wave << 4;

    // persistent W_hh A-frags (K=128 -> 4)
    half8 Ahh[4];
    #pragma unroll
    for (int kt = 0; kt < 4; ++kt) {
        const float* wr = Whh + (jbase + lb) * DH + kt * 32 + lg * 8;
        half8 f;
        #pragma unroll
        for (int i = 0; i < 8; ++i) f[i] = (_Float16)wr[i];
        Ahh[kt] = f;
    }

    // xp ring: per lane 4 f16 = xp[t][bbase+lb][jbase + lg*4 .. +3]
    const _Float16* xpp = xp + (size_t)(bbase + lb) * DH + jbase + (lg << 2);
    const size_t XPS = (size_t)BATCH * DH;

    half4v xq1, xq2, xq3;
    f32x4 ci;   // f32 xp[t], C-in of chain 1
    {
        half4v x0 = *(const half4v*)(xpp);
        xq1 = *(const half4v*)(xpp + 1 * XPS);
        xq2 = *(const half4v*)(xpp + 2 * XPS);
        xq3 = *(const half4v*)(xpp + 3 * XPS);
        ci = cvt4f(x0);
    }
    const _Float16* xload = xpp + 4 * XPS;   // -> xp[min(t+4, SEQ-1)]

    half8 hf0, hf1, hf2, hf3;
    {
        half8 z;
        #pragma unroll
        for (int i = 0; i < 8; ++i) z[i] = (_Float16)0.0f;
        hf0 = hf1 = hf2 = hf3 = z;   // h_0 = 0
    }

    const int woff  = hoff(lb, jbase + (lg << 2));
    const int roff0 = hoff(lb, 0 * 32 + (lg << 3));
    const int roff1 = hoff(lb, 1 * 32 + (lg << 3));
    const int roff2 = hoff(lb, 2 * 32 + (lg << 3));
    const int roff3 = hoff(lb, 3 * 32 + (lg << 3));

    #pragma unroll 2
    for (int t = 0; t < SEQ - 1; ++t) {
        const int nb = (t + 1) & 1;
        char* hb = hbuf + nb * 4096;

        // hh: 2 independent depth-2 chains; chain1 C-in = xp[t] (+bias folded in)
        f32x4 zz = {0.0f, 0.0f, 0.0f, 0.0f};
        f32x4 acc1, acc2;
        acc1 = __builtin_amdgcn_mfma_f32_16x16x32_f16(Ahh[0], hf0, ci,   0, 0, 0);
        acc2 = __builtin_amdgcn_mfma_f32_16x16x32_f16(Ahh[2], hf2, zz,   0, 0, 0);
        acc1 = __builtin_amdgcn_mfma_f32_16x16x32_f16(Ahh[1], hf1, acc1, 0, 0, 0);
        acc2 = __builtin_amdgcn_mfma_f32_16x16x32_f16(Ahh[3], hf3, acc2, 0, 0, 0);

        // prefetch xp[t+4] (clamped at tail; extra loads of last row unused)
        half4v xnew = *(const half4v*)xload;
        if (t + 5 < SEQ) xload += XPS;

        // h_{t+1} = tanh(z) -> fp16 -> LDS
        f32x4 rA;
        #pragma unroll
        for (int r = 0; r < 4; ++r) rA[r] = fast_tanh(acc1[r] + acc2[r]);
        *(half4v*)(hb + woff) = pack4(rA);

        // rotate ring; ci <- xp[t+1] (off critical path)
        ci = cvt4f(xq1);
        xq1 = xq2; xq2 = xq3; xq3 = xnew;

        // publish h_{t+1}; manual lgkm-only drain (no vmcnt -> xp loads stay in flight)
        asm volatile("s_waitcnt lgkmcnt(0)" ::: "memory");
        __builtin_amdgcn_s_barrier();
        asm volatile("" ::: "memory");

        hf0 = *(const half8*)(hb + roff0);
        hf2 = *(const half8*)(hb + roff2);
        hf1 = *(const half8*)(hb + roff1);
        hf3 = *(const half8*)(hb + roff3);
    }

    // epilogue: t = SEQ-1 -> h_final -> out (f32)
    {
        f32x4 zz = {0.0f, 0.0f, 0.0f, 0.0f};
        f32x4 acc1, acc2;
        acc1 = __builtin_amdgcn_mfma_f32_16x16x32_f16(Ahh[0], hf0, ci,   0, 0, 0);
        acc2 = __builtin_amdgcn_mfma_f32_16x16x32_f16(Ahh[2], hf2, zz,   0, 0, 0);
        acc1 = __builtin_amdgcn_mfma_f32_16x16x32_f16(Ahh[1], hf1, acc1, 0, 0, 0);
        acc2 = __builtin_amdgcn_mfma_f32_16x16x32_f16(Ahh[3], hf3, acc2, 0, 0, 0);
        f32x4 rA;
        #pragma unroll
        for (int r = 0; r < 4; ++r) rA[r] = fast_tanh(acc1[r] + acc2[r]);
        *(f32x4*)(out + (size_t)(bbase + lb) * DH + jbase + (lg << 2)) = rA;
    }
}

// ---------------------------------------------------------------------------
// Fallback (R2 fused, proven 1768 us) if d_ws < 256 MB.
// ---------------------------------------------------------------------------
__device__ __forceinline__ int hoffc(int b, int chunk, int lo) {
    return b * 256 + ((chunk ^ b) << 4) + lo;
}
__device__ __forceinline__ int xoff_lds(int b, int chunk, int lo) {
    return b * 128 + (((chunk ^ (b & 7)) << 4) + lo);
}

__launch_bounds__(512, 1)
__global__ void rnn_fused_scan_r2(const float* __restrict__ x,
                                  const float* __restrict__ Wih,
                                  const float* __restrict__ bih,
                                  const float* __restrict__ Whh,
                                  const float* __restrict__ bhh,
                                  float* __restrict__ out)
{
    __shared__ __align__(16) char lds[12288];
    char* hbuf = lds;
    char* xbuf = lds + 8192;

    const int tid   = threadIdx.x;
    const int wave  = tid >> 6;
    const int lane  = tid & 63;
    const int lb    = lane & 15;
    const int lg    = lane >> 4;
    const int bbase = blockIdx.x << 4;
    const int jbase = wave << 4;

    half8 Ahh[4], Aih[2];
    #pragma unroll
    for (int kt = 0; kt < 4; ++kt) {
        const float* wr = Whh + (jbase + lb) * DH + kt * 32 + lg * 8;
        half8 f;
        #pragma unroll
        for (int i = 0; i < 8; ++i) f[i] = (_Float16)wr[i];
        Ahh[kt] = f;
    }
    #pragma unroll
    for (int kt = 0; kt < 2; ++kt) {
        const float* wr = Wih + (jbase + lb) * DIN + kt * 32 + lg * 8;
        half8 f;
        #pragma unroll
        for (int i = 0; i < 8; ++i) f[i] = (_Float16)wr[i];
        Aih[kt] = f;
    }
    f32x4 bias;
    #pragma unroll
    for (int r = 0; r < 4; ++r) {
        int j = jbase + lg * 4 + r;
        bias[r] = bih[j] + bhh[j];
    }

    const int bx = tid >> 5;
    const int kx = (tid & 31) << 1;
    const float* xlane = x + (size_t)(bbase + bx) * DIN + kx;

    f32x2 r0  = *(const f32x2*)(xlane + 0 * (size_t)XSTEP);
    f32x2 rx0 = *(const f32x2*)(xlane + 1 * (size_t)XSTEP);
    f32x2 rx1 = *(const f32x2*)(xlane + 2 * (size_t)XSTEP);
    f32x2 rx2 = *(const f32x2*)(xlane + 3 * (size_t)XSTEP);
    {
        half2v p; p[0] = (_Float16)r0[0]; p[1] = (_Float16)r0[1];
        *(half2v*)(xbuf + xoff_lds(bx, kx >> 3, (kx & 7) * 2)) = p;
    }
    const float* xload = xlane + 4 * (size_t)XSTEP;

    half8 hf0, hf1, hf2, hf3, xf0, xf1;
    {
        half8 z;
        #pragma unroll
        for (int i = 0; i < 8; ++i) z[i] = (_Float16)0.0f;
        hf0 = hf1 = hf2 = hf3 = z;
    }

    asm volatile("s_waitcnt lgkmcnt(0)" ::: "memory");
    __builtin_amdgcn_s_barrier();
    asm volatile("" ::: "memory");
    xf0 = *(const half8*)(xbuf + xoff_lds(lb, 0 * 4 + lg, 0));
    xf1 = *(const half8*)(xbuf + xoff_lds(lb, 1 * 4 + lg, 0));

    f32x4 acc_ih;
    acc_ih = __builtin_amdgcn_mfma_f32_16x16x32_f16(Aih[0], xf0, bias,   0, 0, 0);
    acc_ih = __builtin_amdgcn_mfma_f32_16x16x32_f16(Aih[1], xf1, acc_ih, 0, 0, 0);

    #pragma unroll 2
    for (int t = 0; t < SEQ - 1; ++t) {
        f32x4 zz = {0.0f, 0.0f, 0.0f, 0.0f};
        f32x4 acc1, acc2;
        acc1 = __builtin_amdgcn_mfma_f32_16x16x32_f16(Ahh[0], hf0, acc_ih, 0, 0, 0);
        acc2 = __builtin_amdgcn_mfma_f32_16x16x32_f16(Ahh[2], hf2, zz,     0, 0, 0);
        acc1 = __builtin_amdgcn_mfma_f32_16x16x32_f16(Ahh[1], hf1, acc1,   0, 0, 0);
        acc2 = __builtin_amdgcn_mfma_f32_16x16x32_f16(Ahh[3], hf3, acc2,   0, 0, 0);

        const int nb = (t + 1) & 1;
        {
            half2v p; p[0] = (_Float16)rx0[0]; p[1] = (_Float16)rx0[1];
            *(half2v*)(xbuf + nb * 2048 + xoff_lds(bx, kx >> 3, (kx & 7) * 2)) = p;
        }
        rx0 = rx1; rx1 = rx2;
        rx2 = *(const f32x2*)xload;
        if (t + 5 < SEQ) xload += XSTEP;

        f32x4 hv;
        #pragma unroll
        for (int r = 0; r < 4; ++r) hv[r] = fast_tanh(acc1[r] + acc2[r]);
        {
            half4v p;
            #pragma unroll
            for (int r = 0; r < 4; ++r) p[r] = (_Float16)hv[r];
            *(half4v*)(hbuf + nb * 4096 + hoffc(lb, (wave << 1) + (lg >> 1), (lg & 1) * 8)) = p;
        }

        asm volatile("s_waitcnt lgkmcnt(0)" ::: "memory");
        __builtin_amdgcn_s_barrier();
        asm volatile("" ::: "memory");

        hf0 = *(const half8*)(hbuf + nb * 4096 + hoffc(lb, 0 * 4 + lg, 0));
        hf2 = *(const half8*)(hbuf + nb * 4096 + hoffc(lb, 2 * 4 + lg, 0));
        hf1 = *(const half8*)(hbuf + nb * 4096 + hoffc(lb, 1 * 4 + lg, 0));
        hf3 = *(const half8*)(hbuf + nb * 4096 + hoffc(lb, 3 * 4 + lg, 0));
        xf0 = *(const half8*)(xbuf + nb * 2048 + xoff_lds(lb, 0 * 4 + lg, 0));
        xf1 = *(const half8*)(xbuf + nb * 2048 + xoff_lds(lb, 1 * 4 + lg, 0));

        acc_ih = __builtin_amdgcn_mfma_f32_16x16x32_f16(Aih[0], xf0, bias,   0, 0, 0);
        acc_ih = __builtin_amdgcn_mfma_f32_16x16x32_f16(Aih[1], xf1, acc_ih, 0, 0, 0);
    }

    {
        f32x4 zz = {0.0f, 0.0f, 0.0f, 0.0f};
        f32x4 acc1, acc2;
        acc1 = __builtin_amdgcn_mfma_f32_16x16x32_f16(Ahh[0], hf0, acc_ih, 0, 0, 0);
        acc2 = __builtin_amdgcn_mfma_f32_16x16x32_f16(Ahh[2], hf2, zz,     0, 0, 0);
        acc1 = __builtin_amdgcn_mfma_f32_16x16x32_f16(Ahh[1], hf1, acc1,   0, 0, 0);
        acc2 = __builtin_amdgcn_mfma_f32_16x16x32_f16(Ahh[3], hf3, acc2,   0, 0, 0);
        f32x4 res;
        #pragma unroll
        for (int r = 0; r < 4; ++r) res[r] = fast_tanh(acc1[r] + acc2[r]);
        *(f32x4*)(out + (size_t)(bbase + lb) * DH + jbase + (lg << 2)) = res;
    }
}

extern "C" void kernel_launch(void* const* d_in, const int* in_sizes, int n_in,
                              void* d_out, int out_size, void* d_ws, size_t ws_size,
                              hipStream_t stream) {
    const float* x   = (const float*)d_in[0];
    const float* Wih = (const float*)d_in[1];
    const float* bih = (const float*)d_in[2];
    const float* Whh = (const float*)d_in[3];
    const float* bhh = (const float*)d_in[4];
    float* out = (float*)d_out;

    if (ws_size >= XP_BYTES) {
        _Float16* xp = (_Float16*)d_ws;
        rnn_prepass<<<SEQ * BATCH / 256, 256, 0, stream>>>(x, Wih, bih, bhh, xp);
        rnn_scan_xp<<<16, 512, 0, stream>>>(xp, Whh, out);
    } else {
        rnn_fused_scan_r2<<<16, 512, 0, stream>>>(x, Wih, bih, Whh, bhh, out);
    }
}

// Round 10
// 1257.568 us; speedup vs baseline: 1.7552x; 1.0450x over previous
//
#include <hip/hip_runtime.h>

// R10: two-kernel scheme (R7/R9 structure).
//  (1) rnn_prepass v4: FAT-16 blocks. 1024 blocks x 1024 rows (4 waves x 256
//      rows = 16 row-tiles each), weights loaded once per wave, depth-2 x
//      prefetch. Target: approach the 524MB/6.3TBps ~83us BW floor.
//  (2) rnn_scan_xp: R5/R7/R9 body (656 cy/step) with #pragma unroll 6:
//      ring period 3 x nb period 2 -> full register renaming, no ring v_movs.
//  Fallback to the proven R2 fused kernel if ws_size < 256 MB.

#define SEQ   4096
#define BATCH 256
#define DIN   64
#define DH    128
#define XSTEP (BATCH * DIN)
#define XP_BYTES ((size_t)SEQ * BATCH * DH * 2)

typedef _Float16 half8  __attribute__((ext_vector_type(8)));
typedef _Float16 half4v __attribute__((ext_vector_type(4)));
typedef _Float16 half2v __attribute__((ext_vector_type(2)));
typedef __fp16   fp16x2 __attribute__((ext_vector_type(2)));
typedef float    f32x4  __attribute__((ext_vector_type(4)));
typedef float    f32x2  __attribute__((ext_vector_type(2)));

union H2 { fp16x2 q; half2v h; unsigned int u; };

// tanh(x) = 1 - 2/(1 + e^{2x}); overflow-free for all finite x.
__device__ __forceinline__ float fast_tanh(float v) {
    float e = __builtin_amdgcn_exp2f(v * 2.88539008177792681472f);
    return 1.0f - 2.0f * __builtin_amdgcn_rcpf(e + 1.0f);
}

__device__ __forceinline__ half2v pk(float a, float b) {
    H2 u; u.q = __builtin_amdgcn_cvt_pkrtz(a, b);
    return u.h;
}

__device__ __forceinline__ half8 cvt8(f32x4 a, f32x4 b) {
    half2v p0 = pk(a[0], a[1]);
    half2v p1 = pk(a[2], a[3]);
    half2v p2 = pk(b[0], b[1]);
    half2v p3 = pk(b[2], b[3]);
    half8 r;
    r[0] = p0[0]; r[1] = p0[1]; r[2] = p1[0]; r[3] = p1[1];
    r[4] = p2[0]; r[5] = p2[1]; r[6] = p3[0]; r[7] = p3[1];
    return r;
}

__device__ __forceinline__ half4v pack4(f32x4 a) {
    half2v q0 = pk(a[0], a[1]);
    half2v q1 = pk(a[2], a[3]);
    half4v r;
    r[0] = q0[0]; r[1] = q0[1]; r[2] = q1[0]; r[3] = q1[1];
    return r;
}

__device__ __forceinline__ f32x4 cvt4f(half4v v) {
    f32x4 r;
    r[0] = (float)v[0]; r[1] = (float)v[1];
    r[2] = (float)v[2]; r[3] = (float)v[3];
    return r;
}

// byte offset of h[b][j] (f16) in a [16][128] tile; 16B-chunk XOR swizzle by b.
__device__ __forceinline__ int hoff(int b, int j) {
    return b * 256 + ((((j >> 3) ^ b) & 15) << 4) + (j & 7) * 2;
}

struct XSlot { f32x4 v0, v1, v2, v3; };
#define XLOAD(slot, p_) do {                                           \
        (slot).v0 = *(const f32x4*)(p_);                               \
        (slot).v1 = *(const f32x4*)((p_) + 4);                         \
        (slot).v2 = *(const f32x4*)((p_) + 32);                        \
        (slot).v3 = *(const f32x4*)((p_) + 36);                        \
    } while (0)

// ---------------------------------------------------------------------------
// Kernel 1: prepass GEMM, v4 fat-16 blocks.
// Block = 4 waves x 1024 rows; wave w handles rows [blk*1024 + w*256, +256)
// as 16 row-tiles of 16, weights loaded once, depth-2 x prefetch.
// ---------------------------------------------------------------------------
__launch_bounds__(256)
__global__ void rnn_prepass(const float* __restrict__ x,     // [SEQ*BATCH][DIN]
                            const float* __restrict__ Wih,   // [DH][DIN]
                            const float* __restrict__ bih,   // [DH]
                            const float* __restrict__ bhh,   // [DH]
                            _Float16* __restrict__ xp)       // [SEQ*BATCH][DH]
{
    const int tid  = threadIdx.x;
    const int w    = tid >> 6;
    const int lane = tid & 63;
    const int lb   = lane & 15;
    const int lg   = lane >> 4;
    const int wbase = blockIdx.x * 1024 + w * 256;   // this wave's 256-row span

    // A-frags: Wih for 8 j-subtiles x 2 k-halves (loaded ONCE per 256 rows)
    half8 A[8][2];
    #pragma unroll
    for (int s = 0; s < 8; ++s) {
        #pragma unroll
        for (int kt = 0; kt < 2; ++kt) {
            const float* wr = Wih + (s * 16 + lb) * DIN + kt * 32 + lg * 8;
            half8 f;
            #pragma unroll
            for (int i = 0; i < 8; ++i) f[i] = (_Float16)wr[i];
            A[s][kt] = f;
        }
    }
    f32x4 bias[8];
    #pragma unroll
    for (int s = 0; s < 8; ++s)
        #pragma unroll
        for (int r = 0; r < 4; ++r) {
            int j = s * 16 + lg * 4 + r;
            bias[s][r] = bih[j] + bhh[j];
        }

    // depth-2 software pipeline over 16 row-tiles
    XSlot ring[2];
    XLOAD(ring[0], x + (size_t)(wbase + 0 * 16 + lb) * DIN + lg * 8);
    XLOAD(ring[1], x + (size_t)(wbase + 1 * 16 + lb) * DIN + lg * 8);

    #pragma unroll
    for (int r = 0; r < 16; ++r) {
        const int row0 = wbase + r * 16;
        XSlot cur = ring[r & 1];                       // static under full unroll
        if (r + 2 < 16) {
            XLOAD(ring[r & 1], x + (size_t)(row0 + 32 + lb) * DIN + lg * 8);
        }
        half8 xf0 = cvt8(cur.v0, cur.v1);
        half8 xf1 = cvt8(cur.v2, cur.v3);

        _Float16* op = xp + (size_t)(row0 + lb) * DH + lg * 4;
        #pragma unroll
        for (int s = 0; s < 8; ++s) {
            f32x4 acc;
            acc = __builtin_amdgcn_mfma_f32_16x16x32_f16(A[s][0], xf0, bias[s], 0, 0, 0);
            acc = __builtin_amdgcn_mfma_f32_16x16x32_f16(A[s][1], xf1, acc,     0, 0, 0);
            *(half4v*)(op + s * 16) = pack4(acc);
        }
    }
}

// ---------------------------------------------------------------------------
// Kernel 2: the scan. R5/R7/R9 body, unroll 6 (ring x nb renaming).
// ---------------------------------------------------------------------------
__launch_bounds__(512, 1)
__global__ void rnn_scan_xp(const _Float16* __restrict__ xp,  // [SEQ][BATCH][DH]
                            const float* __restrict__ Whh,    // [DH][DH]
                            float* __restrict__ out)          // [BATCH][DH]
{
    __shared__ __align__(16) char hbuf[8192];   // 2 x swizzled [16][128] f16

    const int tid   = threadIdx.x;
    const int wave  = tid >> 6;
    const int lane  = tid & 63;
    const int lb    = lane & 15;
    const int lg    = lane >> 4;
    const int bbase = blockIdx.x << 4;
    const int jbase = wave << 4;

    // persistent W_hh A-frags (K=128 -> 4)
    half8 Ahh[4];
    #pragma unroll
    for (int kt = 0; kt < 4; ++kt) {
        const float* wr = Whh + (jbase + lb) * DH + kt * 32 + lg * 8;
        half8 f;
        #pragma unroll
        for (int i = 0; i < 8; ++i) f[i] = (_Float16)wr[i];
        Ahh[kt] = f;
    }

    // xp ring: per lane 4 f16 = xp[t][bbase+lb][jbase + lg*4 .. +3]
    const _Float16* xpp = xp + (size_t)(bbase + lb) * DH + jbase + (lg << 2);
    const size_t XPS = (size_t)BATCH * DH;

    half4v xq1, xq2, xq3;
    f32x4 ci;   // f32 xp[t], C-in of chain 1
    {
        half4v x0 = *(const half4v*)(xpp);
        xq1 = *(const half4v*)(xpp + 1 * XPS);
        xq2 = *(const half4v*)(xpp + 2 * XPS);
        xq3 = *(const half4v*)(xpp + 3 * XPS);
        ci = cvt4f(x0);
    }
    const _Float16* xload = xpp + 4 * XPS;   // -> xp[min(t+4, SEQ-1)]

    half8 hf0, hf1, hf2, hf3;
    {
        half8 z;
        #pragma unroll
        for (int i = 0; i < 8; ++i) z[i] = (_Float16)0.0f;
        hf0 = hf1 = hf2 = hf3 = z;   // h_0 = 0
    }

    const int woff  = hoff(lb, jbase + (lg << 2));
    const int roff0 = hoff(lb, 0 * 32 + (lg << 3));
    const int roff1 = hoff(lb, 1 * 32 + (lg << 3));
    const int roff2 = hoff(lb, 2 * 32 + (lg << 3));
    const int roff3 = hoff(lb, 3 * 32 + (lg << 3));

    #pragma unroll 6
    for (int t = 0; t < SEQ - 1; ++t) {
        const int nb = (t + 1) & 1;   // compile-time under unroll-6
        char* hb = hbuf + nb * 4096;

        // hh: 2 independent depth-2 chains; chain1 C-in = xp[t] (+bias folded in)
        f32x4 zz = {0.0f, 0.0f, 0.0f, 0.0f};
        f32x4 acc1, acc2;
        acc1 = __builtin_amdgcn_mfma_f32_16x16x32_f16(Ahh[0], hf0, ci,   0, 0, 0);
        acc2 = __builtin_amdgcn_mfma_f32_16x16x32_f16(Ahh[2], hf2, zz,   0, 0, 0);
        acc1 = __builtin_amdgcn_mfma_f32_16x16x32_f16(Ahh[1], hf1, acc1, 0, 0, 0);
        acc2 = __builtin_amdgcn_mfma_f32_16x16x32_f16(Ahh[3], hf3, acc2, 0, 0, 0);

        // prefetch xp[t+4] (clamped at tail; extra loads of last row unused)
        half4v xnew = *(const half4v*)xload;
        if (t + 5 < SEQ) xload += XPS;

        // h_{t+1} = tanh(z) -> fp16 -> LDS
        f32x4 rA;
        #pragma unroll
        for (int r = 0; r < 4; ++r) rA[r] = fast_tanh(acc1[r] + acc2[r]);
        *(half4v*)(hb + woff) = pack4(rA);

        // rotate ring; ci <- xp[t+1] (off critical path)
        ci = cvt4f(xq1);
        xq1 = xq2; xq2 = xq3; xq3 = xnew;

        // publish h_{t+1}; manual lgkm-only drain (no vmcnt -> xp loads stay in flight)
        asm volatile("s_waitcnt lgkmcnt(0)" ::: "memory");
        __builtin_amdgcn_s_barrier();
        asm volatile("" ::: "memory");

        hf0 = *(const half8*)(hb + roff0);
        hf2 = *(const half8*)(hb + roff2);
        hf1 = *(const half8*)(hb + roff1);
        hf3 = *(const half8*)(hb + roff3);
    }

    // epilogue: t = SEQ-1 -> h_final -> out (f32)
    {
        f32x4 zz = {0.0f, 0.0f, 0.0f, 0.0f};
        f32x4 acc1, acc2;
        acc1 = __builtin_amdgcn_mfma_f32_16x16x32_f16(Ahh[0], hf0, ci,   0, 0, 0);
        acc2 = __builtin_amdgcn_mfma_f32_16x16x32_f16(Ahh[2], hf2, zz,   0, 0, 0);
        acc1 = __builtin_amdgcn_mfma_f32_16x16x32_f16(Ahh[1], hf1, acc1, 0, 0, 0);
        acc2 = __builtin_amdgcn_mfma_f32_16x16x32_f16(Ahh[3], hf3, acc2, 0, 0, 0);
        f32x4 rA;
        #pragma unroll
        for (int r = 0; r < 4; ++r) rA[r] = fast_tanh(acc1[r] + acc2[r]);
        *(f32x4*)(out + (size_t)(bbase + lb) * DH + jbase + (lg << 2)) = rA;
    }
}

// ---------------------------------------------------------------------------
// Fallback (R2 fused, proven 1768 us) if d_ws < 256 MB.
// ---------------------------------------------------------------------------
__device__ __forceinline__ int hoffc(int b, int chunk, int lo) {
    return b * 256 + ((chunk ^ b) << 4) + lo;
}
__device__ __forceinline__ int xoff_lds(int b, int chunk, int lo) {
    return b * 128 + (((chunk ^ (b & 7)) << 4) + lo);
}

__launch_bounds__(512, 1)
__global__ void rnn_fused_scan_r2(const float* __restrict__ x,
                                  const float* __restrict__ Wih,
                                  const float* __restrict__ bih,
                                  const float* __restrict__ Whh,
                                  const float* __restrict__ bhh,
                                  float* __restrict__ out)
{
    __shared__ __align__(16) char lds[12288];
    char* hbuf = lds;
    char* xbuf = lds + 8192;

    const int tid   = threadIdx.x;
    const int wave  = tid >> 6;
    const int lane  = tid & 63;
    const int lb    = lane & 15;
    const int lg    = lane >> 4;
    const int bbase = blockIdx.x << 4;
    const int jbase = wave << 4;

    half8 Ahh[4], Aih[2];
    #pragma unroll
    for (int kt = 0; kt < 4; ++kt) {
        const float* wr = Whh + (jbase + lb) * DH + kt * 32 + lg * 8;
        half8 f;
        #pragma unroll
        for (int i = 0; i < 8; ++i) f[i] = (_Float16)wr[i];
        Ahh[kt] = f;
    }
    #pragma unroll
    for (int kt = 0; kt < 2; ++kt) {
        const float* wr = Wih + (jbase + lb) * DIN + kt * 32 + lg * 8;
        half8 f;
        #pragma unroll
        for (int i = 0; i < 8; ++i) f[i] = (_Float16)wr[i];
        Aih[kt] = f;
    }
    f32x4 bias;
    #pragma unroll
    for (int r = 0; r < 4; ++r) {
        int j = jbase + lg * 4 + r;
        bias[r] = bih[j] + bhh[j];
    }

    const int bx = tid >> 5;
    const int kx = (tid & 31) << 1;
    const float* xlane = x + (size_t)(bbase + bx) * DIN + kx;

    f32x2 r0  = *(const f32x2*)(xlane + 0 * (size_t)XSTEP);
    f32x2 rx0 = *(const f32x2*)(xlane + 1 * (size_t)XSTEP);
    f32x2 rx1 = *(const f32x2*)(xlane + 2 * (size_t)XSTEP);
    f32x2 rx2 = *(const f32x2*)(xlane + 3 * (size_t)XSTEP);
    {
        half2v p; p[0] = (_Float16)r0[0]; p[1] = (_Float16)r0[1];
        *(half2v*)(xbuf + xoff_lds(bx, kx >> 3, (kx & 7) * 2)) = p;
    }
    const float* xload = xlane + 4 * (size_t)XSTEP;

    half8 hf0, hf1, hf2, hf3, xf0, xf1;
    {
        half8 z;
        #pragma unroll
        for (int i = 0; i < 8; ++i) z[i] = (_Float16)0.0f;
        hf0 = hf1 = hf2 = hf3 = z;
    }

    asm volatile("s_waitcnt lgkmcnt(0)" ::: "memory");
    __builtin_amdgcn_s_barrier();
    asm volatile("" ::: "memory");
    xf0 = *(const half8*)(xbuf + xoff_lds(lb, 0 * 4 + lg, 0));
    xf1 = *(const half8*)(xbuf + xoff_lds(lb, 1 * 4 + lg, 0));

    f32x4 acc_ih;
    acc_ih = __builtin_amdgcn_mfma_f32_16x16x32_f16(Aih[0], xf0, bias,   0, 0, 0);
    acc_ih = __builtin_amdgcn_mfma_f32_16x16x32_f16(Aih[1], xf1, acc_ih, 0, 0, 0);

    #pragma unroll 2
    for (int t = 0; t < SEQ - 1; ++t) {
        f32x4 zz = {0.0f, 0.0f, 0.0f, 0.0f};
        f32x4 acc1, acc2;
        acc1 = __builtin_amdgcn_mfma_f32_16x16x32_f16(Ahh[0], hf0, acc_ih, 0, 0, 0);
        acc2 = __builtin_amdgcn_mfma_f32_16x16x32_f16(Ahh[2], hf2, zz,     0, 0, 0);
        acc1 = __builtin_amdgcn_mfma_f32_16x16x32_f16(Ahh[1], hf1, acc1,   0, 0, 0);
        acc2 = __builtin_amdgcn_mfma_f32_16x16x32_f16(Ahh[3], hf3, acc2,   0, 0, 0);

        const int nb = (t + 1) & 1;
        {
            half2v p; p[0] = (_Float16)rx0[0]; p[1] = (_Float16)rx0[1];
            *(half2v*)(xbuf + nb * 2048 + xoff_lds(bx, kx >> 3, (kx & 7) * 2)) = p;
        }
        rx0 = rx1; rx1 = rx2;
        rx2 = *(const f32x2*)xload;
        if (t + 5 < SEQ) xload += XSTEP;

        f32x4 hv;
        #pragma unroll
        for (int r = 0; r < 4; ++r) hv[r] = fast_tanh(acc1[r] + acc2[r]);
        {
            half4v p;
            #pragma unroll
            for (int r = 0; r < 4; ++r) p[r] = (_Float16)hv[r];
            *(half4v*)(hbuf + nb * 4096 + hoffc(lb, (wave << 1) + (lg >> 1), (lg & 1) * 8)) = p;
        }

        asm volatile("s_waitcnt lgkmcnt(0)" ::: "memory");
        __builtin_amdgcn_s_barrier();
        asm volatile("" ::: "memory");

        hf0 = *(const half8*)(hbuf + nb * 4096 + hoffc(lb, 0 * 4 + lg, 0));
        hf2 = *(const half8*)(hbuf + nb * 4096 + hoffc(lb, 2 * 4 + lg, 0));
        hf1 = *(const half8*)(hbuf + nb * 4096 + hoffc(lb, 1 * 4 + lg, 0));
        hf3 = *(const half8*)(hbuf + nb * 4096 + hoffc(lb, 3 * 4 + lg, 0));
        xf0 = *(const half8*)(xbuf + nb * 2048 + xoff_lds(lb, 0 * 4 + lg, 0));
        xf1 = *(const half8*)(xbuf + nb * 2048 + xoff_lds(lb, 1 * 4 + lg, 0));

        acc_ih = __builtin_amdgcn_mfma_f32_16x16x32_f16(Aih[0], xf0, bias,   0, 0, 0);
        acc_ih = __builtin_amdgcn_mfma_f32_16x16x32_f16(Aih[1], xf1, acc_ih, 0, 0, 0);
    }

    {
        f32x4 zz = {0.0f, 0.0f, 0.0f, 0.0f};
        f32x4 acc1, acc2;
        acc1 = __builtin_amdgcn_mfma_f32_16x16x32_f16(Ahh[0], hf0, acc_ih, 0, 0, 0);
        acc2 = __builtin_amdgcn_mfma_f32_16x16x32_f16(Ahh[2], hf2, zz,     0, 0, 0);
        acc1 = __builtin_amdgcn_mfma_f32_16x16x32_f16(Ahh[1], hf1, acc1,   0, 0, 0);
        acc2 = __builtin_amdgcn_mfma_f32_16x16x32_f16(Ahh[3], hf3, acc2,   0, 0, 0);
        f32x4 res;
        #pragma unroll
        for (int r = 0; r < 4; ++r) res[r] = fast_tanh(acc1[r] + acc2[r]);
        *(f32x4*)(out + (size_t)(bbase + lb) * DH + jbase + (lg << 2)) = res;
    }
}

extern "C" void kernel_launch(void* const* d_in, const int* in_sizes, int n_in,
                              void* d_out, int out_size, void* d_ws, size_t ws_size,
                              hipStream_t stream) {
    const float* x   = (const float*)d_in[0];
    const float* Wih = (const float*)d_in[1];
    const float* bih = (const float*)d_in[2];
    const float* Whh = (const float*)d_in[3];
    const float* bhh = (const float*)d_in[4];
    float* out = (float*)d_out;

    if (ws_size >= XP_BYTES) {
        _Float16* xp = (_Float16*)d_ws;
        rnn_prepass<<<SEQ * BATCH / 1024, 256, 0, stream>>>(x, Wih, bih, bhh, xp);
        rnn_scan_xp<<<16, 512, 0, stream>>>(xp, Whh, out);
    } else {
        rnn_fused_scan_r2<<<16, 512, 0, stream>>>(x, Wih, bih, Whh, bhh, out);
    }
}